// Round 5
// baseline (192.274 us; speedup 1.0000x reference)
//
#include <hip/hip_runtime.h>
#include <hip/hip_bf16.h>
#include <math.h>

#define N_ATOMS 10000
#define N_PAIRS 160000
#define FDIM 256
#define GDIM 16
#define HDIM 64
#define HIDDIM 256
#define MLP_IN 640
#define MLP_OUT 258

typedef __attribute__((ext_vector_type(8))) short short8;
typedef __attribute__((ext_vector_type(4))) float f32x4;

__device__ __forceinline__ float gelu_exact(float x) {
    return 0.5f * x * (1.0f + erff(x * 0.70710678118654752f));
}

// ---------------------------------------------------------------------------
// Prep: f32 -> bf16 conversions + agh transpose + W3 pad + zero histogram.
// ---------------------------------------------------------------------------
#define PREP_TOTAL (2560000 + 163840 + 65536 + 262144 + 81920 + 10000)
__global__ void prep_kernel(const float* __restrict__ emb,
                            const float* __restrict__ W1,
                            const float* __restrict__ W2,
                            const float* __restrict__ agh,
                            const float* __restrict__ W3,
                            __hip_bfloat16* __restrict__ embB,
                            __hip_bfloat16* __restrict__ W1b,
                            __hip_bfloat16* __restrict__ W2b,
                            __hip_bfloat16* __restrict__ aghT,
                            __hip_bfloat16* __restrict__ W3b,
                            int* __restrict__ cnt) {
    int tid = blockIdx.x * blockDim.x + threadIdx.x;
    if (tid >= PREP_TOTAL) return;
    int j = tid;
    if (j < 2560000) { embB[j] = __float2bfloat16(emb[j]); return; }
    j -= 2560000;
    if (j < 163840) { W1b[j] = __float2bfloat16(W1[j]); return; }
    j -= 163840;
    if (j < 65536) { W2b[j] = __float2bfloat16(W2[j]); return; }
    j -= 65536;
    if (j < 262144) {
        int n = j >> 8, k = j & 255;
        aghT[j] = __float2bfloat16(agh[k * 1024 + n]);
        return;
    }
    j -= 262144;
    if (j < 81920) {
        int n = j >> 8;
        W3b[j] = (n < MLP_OUT) ? __float2bfloat16(W3[j]) : __float2bfloat16(0.f);
        return;
    }
    j -= 81920;
    cnt[j] = 0;
}

// ---------------------------------------------------------------------------
// Count-sort of pairs by destination atom: hist -> scan -> scatter_ids.
// ---------------------------------------------------------------------------
__global__ void hist_kernel(const int* __restrict__ idx_j, int* __restrict__ cnt) {
    int p = blockIdx.x * blockDim.x + threadIdx.x;
    if (p >= N_PAIRS) return;
    atomicAdd(&cnt[idx_j[p]], 1);
}

// Exclusive scan of cnt[10000] -> start, cursor. Single block of 1024.
__global__ __launch_bounds__(1024) void scan_kernel(const int* __restrict__ cnt,
                                                    int* __restrict__ start,
                                                    int* __restrict__ cursor) {
    __shared__ int part[1024];
    int t = threadIdx.x;
    int base = t * 10;
    int pre[10];
    int sum = 0;
#pragma unroll
    for (int k = 0; k < 10; ++k) {
        int i = base + k;
        int v = (i < N_ATOMS) ? cnt[i] : 0;
        pre[k] = sum;
        sum += v;
    }
    part[t] = sum;
    __syncthreads();
    for (int off = 1; off < 1024; off <<= 1) {
        int v = (t >= off) ? part[t - off] : 0;
        __syncthreads();
        part[t] += v;
        __syncthreads();
    }
    int excl = (t == 0) ? 0 : part[t - 1];
#pragma unroll
    for (int k = 0; k < 10; ++k) {
        int i = base + k;
        if (i < N_ATOMS) {
            start[i]  = excl + pre[k];
            cursor[i] = excl + pre[k];
        }
    }
}

__global__ void scatter_ids_kernel(const int* __restrict__ idx_j,
                                   int* __restrict__ cursor,
                                   int* __restrict__ sorted) {
    int p = blockIdx.x * blockDim.x + threadIdx.x;
    if (p >= N_PAIRS) return;
    int i = idx_j[p];
    int pos = atomicAdd(&cursor[i], 1);
    sorted[pos] = p;
}

// Gather: 16 lanes per atom, float4 per lane over [gs(16) | gv(48)].
// Plain stores -> no zeroing of Gs/GV needed.
__global__ void gather_kernel(const int* __restrict__ sorted,
                              const int* __restrict__ start,
                              const int* __restrict__ cnt,
                              const float* __restrict__ gs,
                              const float* __restrict__ gv,
                              float* __restrict__ Gs_sum,
                              float* __restrict__ GV_sum) {
    int t = threadIdx.x;
    int grp = t >> 4;
    int l = t & 15;
    int atom = blockIdx.x * 16 + grp;
    if (atom >= N_ATOMS) return;
    int s = start[atom];
    int c = cnt[atom];
    const float* base;
    long long stride;
    if (l < 4) { base = gs + l * 4;        stride = 16; }
    else       { base = gv + (l - 4) * 4;  stride = 48; }
    f32x4 acc = {0.f, 0.f, 0.f, 0.f};
    int j = 0;
    for (; j + 1 < c; j += 2) {
        int p0 = sorted[s + j];
        int p1 = sorted[s + j + 1];
        f32x4 v0 = *(const f32x4*)(base + p0 * stride);
        f32x4 v1 = *(const f32x4*)(base + p1 * stride);
        acc += v0;
        acc += v1;
    }
    if (j < c) {
        int p0 = sorted[s + j];
        acc += *(const f32x4*)(base + p0 * stride);
    }
    float* dst = (l < 4) ? (Gs_sum + atom * 16 + l * 4)
                         : (GV_sum + atom * 48 + (l - 4) * 4);
    *(f32x4*)dst = acc;
}

// ---------------------------------------------------------------------------
// bf16 MFMA GEMM: C[M,N] = A[M,K] @ B[N,K]^T, f32 accumulate.
// Block: 256 thr = 4 waves; block tile 128x64; wave tile 32x64 (2x4 frags).
// MODE 0: store bf16   MODE 1: +bias, gelu, store bf16   MODE 2: +bias, remap
// ---------------------------------------------------------------------------
template<int MODE, int M, int N, int K>
__global__ __launch_bounds__(256) void gemm_mfma(const short* __restrict__ A,
                                                 const short* __restrict__ B,
                                                 const float* __restrict__ bias,
                                                 void* __restrict__ Cout) {
    int lane = threadIdx.x & 63;
    int wave = threadIdx.x >> 6;
    int m0 = blockIdx.x * 128 + wave * 32;
    int n0 = blockIdx.y * 64;
    int lr = lane & 15;
    int koff0 = (lane >> 4) * 8;

    f32x4 acc[2][4] = {};
    const short8 zero8 = {};

    const short* A0 = A + (long long)(m0 + lr) * K + koff0;
    const short* A1 = A + (long long)(m0 + 16 + lr) * K + koff0;
    const short* Bb = B + (long long)(n0 + lr) * K + koff0;
    bool ok0 = (m0 + lr) < M;
    bool ok1 = (m0 + 16 + lr) < M;

#pragma unroll 2
    for (int ks = 0; ks < K; ks += 32) {
        short8 a0 = ok0 ? *(const short8*)(A0 + ks) : zero8;
        short8 a1 = ok1 ? *(const short8*)(A1 + ks) : zero8;
        short8 b0 = *(const short8*)(Bb + ks);
        short8 b1 = *(const short8*)(Bb + 16 * K + ks);
        short8 b2 = *(const short8*)(Bb + 32 * K + ks);
        short8 b3 = *(const short8*)(Bb + 48 * K + ks);
        acc[0][0] = __builtin_amdgcn_mfma_f32_16x16x32_bf16(a0, b0, acc[0][0], 0, 0, 0);
        acc[0][1] = __builtin_amdgcn_mfma_f32_16x16x32_bf16(a0, b1, acc[0][1], 0, 0, 0);
        acc[0][2] = __builtin_amdgcn_mfma_f32_16x16x32_bf16(a0, b2, acc[0][2], 0, 0, 0);
        acc[0][3] = __builtin_amdgcn_mfma_f32_16x16x32_bf16(a0, b3, acc[0][3], 0, 0, 0);
        acc[1][0] = __builtin_amdgcn_mfma_f32_16x16x32_bf16(a1, b0, acc[1][0], 0, 0, 0);
        acc[1][1] = __builtin_amdgcn_mfma_f32_16x16x32_bf16(a1, b1, acc[1][1], 0, 0, 0);
        acc[1][2] = __builtin_amdgcn_mfma_f32_16x16x32_bf16(a1, b2, acc[1][2], 0, 0, 0);
        acc[1][3] = __builtin_amdgcn_mfma_f32_16x16x32_bf16(a1, b3, acc[1][3], 0, 0, 0);
    }

    // C/D layout: col = lane&15, row = (lane>>4)*4 + r
    float* outp = (float*)Cout;
    __hip_bfloat16* outb = (__hip_bfloat16*)Cout;
    int rbase = (lane >> 4) * 4;
#pragma unroll
    for (int f2 = 0; f2 < 2; ++f2) {
#pragma unroll
        for (int g = 0; g < 4; ++g) {
            int col = n0 + g * 16 + lr;
            if (MODE == 2 && col >= MLP_OUT) continue;
#pragma unroll
            for (int r = 0; r < 4; ++r) {
                int row = m0 + f2 * 16 + rbase + r;
                if (row >= M) continue;
                float v = acc[f2][g][r];
                if (MODE == 0) {
                    outb[(long long)row * N + col] = __float2bfloat16(v);
                } else if (MODE == 1) {
                    v += bias[col];
                    outb[(long long)row * N + col] = __float2bfloat16(gelu_exact(v));
                } else {
                    v += bias[col];
                    if (col == 0)      outp[2560000 + row] = v;
                    else if (col == 1) outp[2570000 + row] = v;
                    else               outp[(long long)row * 256 + (col - 2)] = v;
                }
            }
        }
    }
}

// ---------------------------------------------------------------------------
// Build "combined" (N x 640 bf16): [radial_emb | vector_emb | radial_q | 0]
// ---------------------------------------------------------------------------
__global__ void build_combined(const float* __restrict__ emb,
                               const float* __restrict__ q,
                               const float* __restrict__ W_gs,
                               const float* __restrict__ Gs_sum,
                               const float* __restrict__ GV_sum,
                               const __hip_bfloat16* __restrict__ Mmat,
                               __hip_bfloat16* __restrict__ combined) {
    __shared__ float sW[FDIM * 17];
    __shared__ float sG[GDIM];
    __shared__ float sGV[48];
    int i = blockIdx.x;
    int t = threadIdx.x;

    for (int j = t; j < FDIM * GDIM; j += 256) {
        int f = j >> 4, g = j & 15;
        sW[f * 17 + g] = W_gs[j];
    }
    if (t < GDIM) sG[t] = Gs_sum[i * GDIM + t];
    if (t < 48)  sGV[t] = GV_sum[i * 48 + t];
    __syncthreads();

    float S = 0.f;
#pragma unroll
    for (int g = 0; g < GDIM; ++g) S += sG[g] * sW[t * 17 + g];

    float e  = emb[(long long)i * FDIM + t];
    float qq = q[i];
    __hip_bfloat16* crow = combined + (long long)i * MLP_IN;
    crow[t]       = __float2bfloat16(e * S);
    crow[320 + t] = __float2bfloat16(qq * S);

    if (t < HDIM) {
        float a0 = 0.f, a1 = 0.f, a2 = 0.f;
#pragma unroll
        for (int g = 0; g < GDIM; ++g) {
            float mg = __bfloat162float(Mmat[(long long)i * 1024 + g * 64 + t]);
            a0 += mg * sGV[0 * 16 + g];
            a1 += mg * sGV[1 * 16 + g];
            a2 += mg * sGV[2 * 16 + g];
        }
        crow[256 + t] = __float2bfloat16(sqrtf(a0 * a0 + a1 * a1 + a2 * a2));
        crow[576 + t] = __float2bfloat16(0.f);
    }
}

extern "C" void kernel_launch(void* const* d_in, const int* in_sizes, int n_in,
                              void* d_out, int out_size, void* d_ws, size_t ws_size,
                              hipStream_t stream) {
    const float* emb  = (const float*)d_in[0];
    const float* q    = (const float*)d_in[1];
    const int*   pidx = (const int*)d_in[2];
    const float* gs   = (const float*)d_in[3];
    const float* gv   = (const float*)d_in[4];
    const float* agh  = (const float*)d_in[5];
    const float* W_gs = (const float*)d_in[6];
    const float* W1   = (const float*)d_in[7];
    const float* b1   = (const float*)d_in[8];
    const float* W2   = (const float*)d_in[9];
    const float* b2   = (const float*)d_in[10];
    const float* W3   = (const float*)d_in[11];
    const float* b3   = (const float*)d_in[12];
    float* out = (float*)d_out;
    float* ws  = (float*)d_ws;

    // Workspace layout (float-slot offsets). h1b/h2b ALIAS the Mmat region:
    // Mmat (5,120,000 f) is dead after build_combined; h1b+h2b need 2,560,000 f.
    // Peak footprint: 10,716,720 floats = 42.9 MB (round-2's 49.9 MB passed;
    // round-4's 53.1 MB overflowed ws and corrupted a neighbor buffer).
    float* Gs_sum = ws;                                        // 160,000 f
    float* GV_sum = ws + 160000;                               // 480,000 f
    int*   cnt    = (int*)(ws + 640000);                       // 10,000
    int*   startA = (int*)(ws + 650000);                       // 10,000
    int*   cursor = (int*)(ws + 660000);                       // 10,000
    int*   sorted = (int*)(ws + 670000);                       // 160,000
    __hip_bfloat16* Mmat = (__hip_bfloat16*)(ws + 830000);     // 10000x1024 bf16
    __hip_bfloat16* h1b  = (__hip_bfloat16*)(ws + 830000);     //   aliases Mmat[0:]
    __hip_bfloat16* h2b  = (__hip_bfloat16*)(ws + 2110000);    //   aliases Mmat[2.56M:]
    __hip_bfloat16* embB = (__hip_bfloat16*)(ws + 5950000);    // 10000x256 bf16
    __hip_bfloat16* aghT = (__hip_bfloat16*)(ws + 7230000);    // 1024x256 bf16
    __hip_bfloat16* W1b  = (__hip_bfloat16*)(ws + 7361072);    // 256x640 bf16
    __hip_bfloat16* W2b  = (__hip_bfloat16*)(ws + 7442992);    // 256x256 bf16
    __hip_bfloat16* W3b  = (__hip_bfloat16*)(ws + 7475760);    // 320x256 bf16
    __hip_bfloat16* comb = (__hip_bfloat16*)(ws + 7516720);    // 10000x640 bf16
    // end: 10,716,720 floats

    const int* idx_j = pidx + N_PAIRS;

    {   // bf16 conversions + transposes + cnt zeroing
        int blocks = (PREP_TOTAL + 255) / 256;
        prep_kernel<<<blocks, 256, 0, stream>>>(emb, W1, W2, agh, W3,
                                                embB, W1b, W2b, aghT, W3b, cnt);
    }
    {   // count-sort pairs by atom
        int blocks = (N_PAIRS + 255) / 256;
        hist_kernel<<<blocks, 256, 0, stream>>>(idx_j, cnt);
        scan_kernel<<<1, 1024, 0, stream>>>(cnt, startA, cursor);
        scatter_ids_kernel<<<blocks, 256, 0, stream>>>(idx_j, cursor, sorted);
    }
    {   // Mmat = embB @ aghT^T : (10000x256)@(256x1024) -> bf16
        dim3 grid((N_ATOMS + 127) / 128, 1024 / 64);
        gemm_mfma<0, N_ATOMS, 1024, 256><<<grid, 256, 0, stream>>>(
            (const short*)embB, (const short*)aghT, nullptr, Mmat);
    }
    {   // segment-sums via gather (no atomics, no zeroing)
        int blocks = (N_ATOMS + 15) / 16;
        gather_kernel<<<blocks, 256, 0, stream>>>(sorted, startA, cnt, gs, gv,
                                                  Gs_sum, GV_sum);
    }
    build_combined<<<N_ATOMS, 256, 0, stream>>>(emb, q, W_gs, Gs_sum, GV_sum, Mmat, comb);
    {   // MLP1 + MLP2 (h1b/h2b live in the now-dead Mmat region)
        dim3 grid((N_ATOMS + 127) / 128, HIDDIM / 64);
        gemm_mfma<1, N_ATOMS, HIDDIM, MLP_IN><<<grid, 256, 0, stream>>>(
            (const short*)comb, (const short*)W1b, b1, h1b);
        gemm_mfma<1, N_ATOMS, HIDDIM, HIDDIM><<<grid, 256, 0, stream>>>(
            (const short*)h1b, (const short*)W2b, b2, h2b);
    }
    {   // MLP3 + remap
        dim3 grid((N_ATOMS + 127) / 128, 320 / 64);
        gemm_mfma<2, N_ATOMS, 320, HIDDIM><<<grid, 256, 0, stream>>>(
            (const short*)h2b, (const short*)W3b, b3, out);
    }
}